// Round 16
// baseline (1799.205 us; speedup 1.0000x reference)
//
#include <hip/hip_runtime.h>
#include <cstddef>

#define NN 50000
#define TT 12
#define FIN 128
#define DD 128
#define HH 4
#define EE 800000
#define MTOT (NN * TT)          // 600000 rows, divisible by 64
#define NEG 0.2f

#define BSH 6                   // bucket = dst >> 6 (64 nodes per bucket)
#define NB 782                  // ceil(50000/64)
#define CAPB 1536               // fixed region entries per (t,bucket); mean 1023, 16 sigma margin
#define BMAX CAPB
#define EPB2 8192               // edges per fill block
#define FB2 98                  // 98*8192 >= 800000
#define GGRID (TT * NB)         // 9384 = 8 * 1173 exactly
#define GPX (GGRID / 8)         // 1173 blocks per XCD slice

typedef __attribute__((ext_vector_type(8))) short bf16x8;
typedef __attribute__((ext_vector_type(4))) float f32x4;

__device__ __forceinline__ ushort f2b(float x) {
    unsigned int u = __builtin_bit_cast(unsigned int, x);
    unsigned int r = (u + 0x7FFFu + ((u >> 16) & 1u)) >> 16;
    return (ushort)r;
}
__device__ __forceinline__ float b2f(ushort u) {
    unsigned int v = ((unsigned int)u) << 16;
    return __builtin_bit_cast(float, v);
}

// ---------------- prep: W_gat in MFMA fragment order, hi/lo bf16 split ----------------
__global__ __launch_bounds__(256) void prep_wg_kernel(
    const float* __restrict__ Wg, ushort* __restrict__ Wgh, ushort* __restrict__ Wgl)
{
    int idx = blockIdx.x * 256 + threadIdx.x;      // < 16384
    int fi = idx >> 9, rem = idx & 511;
    int l = rem >> 3, j = rem & 7;
    int kb = fi >> 3, cf = fi & 7;
    int k = kb * 32 + (l >> 4) * 8 + j;
    int col = cf * 16 + (l & 15);
    float v = Wg[(size_t)k * DD + col];
    ushort hi = f2b(v);
    Wgh[idx] = hi;
    Wgl[idx] = f2b(v - b2f(hi));
}

// ---------------- all-t GAT GEMM + fused attention logits ----------------
__global__ __launch_bounds__(256) void gemm_all_kernel(
    const float* __restrict__ x, const ushort* __restrict__ Wgh, const ushort* __restrict__ Wgl,
    const float* __restrict__ a_src, const float* __restrict__ a_dst,
    ushort* __restrict__ hbf, float* __restrict__ alsrc, float* __restrict__ aldst)
{
    __shared__ ushort sAh[64 * 128];   // 16 KB
    const int tid = threadIdx.x;
    const int w = tid >> 6, l = tid & 63;
    const int m0 = blockIdx.x * 64;

    #pragma unroll
    for (int i = 0; i < 8; i++) {
        int fl = tid + 256 * i;            // 0..2047 = 64 rows x 32 float4
        int row = fl >> 5, q = fl & 31;
        float4 v = *(const float4*)&x[(size_t)(m0 + row) * FIN + q * 4];
        ushort hi[4] = {f2b(v.x), f2b(v.y), f2b(v.z), f2b(v.w)};
        int byteoff = row * 256 + ((q * 8) ^ ((row & 7) << 4));
        *(uint2*)((char*)sAh + byteoff) = *(uint2*)hi;
    }
    __syncthreads();

    f32x4 acc[4][2];
    #pragma unroll
    for (int i = 0; i < 4; i++)
        #pragma unroll
        for (int s = 0; s < 2; s++) acc[i][s] = (f32x4){0.f, 0.f, 0.f, 0.f};

    const bf16x8* Bh = (const bf16x8*)Wgh;
    const bf16x8* Bl = (const bf16x8*)Wgl;
    #pragma unroll
    for (int kb = 0; kb < 4; kb++) {
        bf16x8 ah[4];
        #pragma unroll
        for (int i = 0; i < 4; i++) {
            int rl = i * 16 + (l & 15);
            int byteoff = rl * 256 + (((kb * 64) + ((l >> 4) * 16)) ^ ((rl & 7) << 4));
            ah[i] = *(const bf16x8*)((const char*)sAh + byteoff);
        }
        bf16x8 bh[2], bl[2];
        #pragma unroll
        for (int s = 0; s < 2; s++) {
            int fi = kb * 8 + 2 * w + s;
            bh[s] = Bh[(size_t)fi * 64 + l];
            bl[s] = Bl[(size_t)fi * 64 + l];
        }
        #pragma unroll
        for (int i = 0; i < 4; i++)
            #pragma unroll
            for (int s = 0; s < 2; s++) {
                acc[i][s] = __builtin_amdgcn_mfma_f32_16x16x32_bf16(ah[i], bh[s], acc[i][s], 0, 0, 0);
                acc[i][s] = __builtin_amdgcn_mfma_f32_16x16x32_bf16(ah[i], bl[s], acc[i][s], 0, 0, 0);
            }
    }

    // hbf write (bf16, t-plane)
    #pragma unroll
    for (int i = 0; i < 4; i++)
        #pragma unroll
        for (int s = 0; s < 2; s++) {
            int jj = (2 * w + s) * 16 + (l & 15);
            #pragma unroll
            for (int r = 0; r < 4; r++) {
                int m = m0 + i * 16 + (l >> 4) * 4 + r;
                int n = m / TT;
                int t = m - n * TT;
                hbf[((size_t)t * NN + n) * DD + jj] = f2b(acc[i][s][r]);
            }
        }

    // fused attention logits: head = w; 16-lane butterfly reduce
    const float as0 = a_src[w * 32 + (l & 15)];
    const float as1 = a_src[w * 32 + 16 + (l & 15)];
    const float ad0 = a_dst[w * 32 + (l & 15)];
    const float ad1 = a_dst[w * 32 + 16 + (l & 15)];
    #pragma unroll
    for (int i = 0; i < 4; i++) {
        #pragma unroll
        for (int r = 0; r < 4; r++) {
            float p1 = acc[i][0][r] * as0 + acc[i][1][r] * as1;
            float p2 = acc[i][0][r] * ad0 + acc[i][1][r] * ad1;
            #pragma unroll
            for (int mk = 1; mk < 16; mk <<= 1) {
                p1 += __shfl_xor(p1, mk);
                p2 += __shfl_xor(p2, mk);
            }
            if ((l & 15) == 0) {
                int m = m0 + i * 16 + (l >> 4) * 4 + r;
                int n = m / TT;
                int t = m - n * TT;
                size_t base = ((size_t)t * NN + n) * 4 + w;
                alsrc[base] = p1;
                aldst[base] = p2;
            }
        }
    }
}

// ---------------- init per-(t,bucket) cursor ----------------
__global__ __launch_bounds__(256) void init_cur_kernel(int* __restrict__ cur)
{
    int i = blockIdx.x * 256 + threadIdx.x;
    if (i < TT * NB) cur[i] = i * CAPB;
}

// ---------------- single-pass bucket fill: LDS histogram + per-(block,bin) cursor runs ----------------
__global__ __launch_bounds__(512) void fill2_kernel(
    const int* __restrict__ ei, int* __restrict__ cur, uint* __restrict__ bbuf)
{
    __shared__ int hcnt[NB];
    __shared__ int hbase[NB];
    const int t = blockIdx.x / FB2;
    const int blk = blockIdx.x - t * FB2;
    const int tid = threadIdx.x;
    const int* srcp = ei + (size_t)t * 2 * EE;
    const int* dstp = srcp + EE;

    for (int b = tid; b < NB; b += 512) hcnt[b] = 0;
    __syncthreads();

    const int ebase = blk * EPB2;
    uint vals[16];
    #pragma unroll
    for (int k = 0; k < 16; k++) {
        int e = ebase + k * 512 + tid;
        uint v = 0xffffffffu;
        if (e < EE) {
            int s = srcp[e];
            int d = dstp[e];
            v = ((uint)d << 16) | (uint)s;
            atomicAdd(&hcnt[d >> BSH], 1);
        }
        vals[k] = v;
    }
    __syncthreads();
    for (int b = tid; b < NB; b += 512) {
        int c = hcnt[b];
        if (c > 0) hbase[b] = atomicAdd(&cur[t * NB + b], c);
        hcnt[b] = 0;
    }
    __syncthreads();
    #pragma unroll
    for (int k = 0; k < 16; k++) {
        uint v = vals[k];
        if (v != 0xffffffffu) {
            int b = v >> 22;
            int r = atomicAdd(&hcnt[b], 1);
            bbuf[hbase[b] + r] = v;
        }
    }
}

// ---------------- fused GAT aggregate, ALL t: in-LDS sort + register accumulate ----------------
__global__ __launch_bounds__(512) void gather_all_kernel(
    const int* __restrict__ cur, const uint* __restrict__ bbuf,
    const float* __restrict__ alsrc_a, const float* __restrict__ aldst_a,
    const uint* __restrict__ hbf32_a, const float* __restrict__ bgat,
    uint* __restrict__ Ag_a)
{
    __shared__ uint ent[BMAX];        // 6 KB
    __shared__ ushort ssrc[BMAX];     // 3 KB
    __shared__ int h64[64];
    __shared__ int p64[65];
    __shared__ int cur64[64];
    const int bid = blockIdx.x;
    const int swz = (bid & 7) * GPX + (bid >> 3);
    const int t = swz / NB;
    const int bkt = swz - t * NB;
    const int ci = t * NB + bkt;
    const int tid = threadIdx.x;
    const int dbase = bkt << BSH;

    const float* alsrc = alsrc_a + (size_t)t * NN * HH;
    const float* aldst = aldst_a + (size_t)t * NN * HH;
    const uint* hbf32 = hbf32_a + (size_t)t * NN * 64;
    uint* Ag = Ag_a + (size_t)t * NN * 64;

    const int lo0 = ci * CAPB;
    int cnt = cur[ci] - lo0;
    if (cnt > BMAX) cnt = BMAX;

    if (tid < 64) h64[tid] = 0;
    __syncthreads();
    for (int i = tid; i < cnt; i += 512) {
        uint e = bbuf[lo0 + i];
        ent[i] = e;
        atomicAdd(&h64[(e >> 16) & 63], 1);
    }
    __syncthreads();
    if (tid < 64) {
        int v = h64[tid];
        #pragma unroll
        for (int off = 1; off < 64; off <<= 1) {
            int u = __shfl_up(v, off);
            if (tid >= off) v += u;
        }
        p64[tid + 1] = v;
        if (tid == 0) p64[0] = 0;
        cur64[tid] = v - h64[tid];   // exclusive prefix
    }
    __syncthreads();
    for (int i = tid; i < cnt; i += 512) {
        uint e = ent[i];
        int pos = atomicAdd(&cur64[(e >> 16) & 63], 1);
        ssrc[pos] = (ushort)(e & 0xffffu);
    }
    __syncthreads();

    const int w = tid >> 6, lane = tid & 63, hd = lane >> 4;
    const float bg0 = bgat[2 * lane], bg1 = bgat[2 * lane + 1];
    for (int q = 0; q < 8; q++) {
        int nd = w * 8 + q;
        int d = dbase + nd;
        if (d >= NN) break;
        float adh = aldst[(size_t)d * 4 + hd];
        // self-loop init
        float a = alsrc[(size_t)d * 4 + hd] + adh;
        a = fmaxf(a, NEG * a);
        float wt = __expf(a);
        float den = wt;
        uint hw = hbf32[(size_t)d * 64 + lane];
        float acc0 = __builtin_bit_cast(float, hw << 16) * wt;
        float acc1 = __builtin_bit_cast(float, hw & 0xffff0000u) * wt;
        const int e1 = p64[nd + 1];
        #pragma unroll 4
        for (int e = p64[nd]; e < e1; e++) {
            int s = ssrc[e];
            float aa = alsrc[(size_t)s * 4 + hd] + adh;
            aa = fmaxf(aa, NEG * aa);
            float wgt = __expf(aa);
            uint hh = hbf32[(size_t)s * 64 + lane];
            acc0 += __builtin_bit_cast(float, hh << 16) * wgt;
            acc1 += __builtin_bit_cast(float, hh & 0xffff0000u) * wgt;
            den += wgt;
        }
        float invd = 1.f / (den + 1e-16f);
        float g0 = fmaxf(acc0 * invd + bg0, 0.f);
        float g1 = fmaxf(acc1 * invd + bg1, 0.f);
        Ag[(size_t)d * 64 + lane] = (uint)f2b(g0) | ((uint)f2b(g1) << 16);
    }
}

// ---------------- prep: bf16 gate matrix in MFMA fragment order ----------------
__global__ __launch_bounds__(256) void prep_b_kernel(
    const float* __restrict__ Wih, const float* __restrict__ Whh, ushort* __restrict__ Bswz)
{
    int idx = blockIdx.x * 256 + threadIdx.x;      // < 131072
    int fi = idx >> 9;
    int rem = idx & 511;
    int l = rem >> 3, j = rem & 7;
    int kb = fi >> 5, c = fi & 31;
    int g = c >> 3, cf = c & 7;
    int k = kb * 32 + (l >> 4) * 8 + j;
    int jj = cf * 16 + (l & 15);
    float v;
    if (g == 0)      v = (k < 128) ? Wih[(size_t)jj * DD + k]         : Whh[(size_t)jj * DD + k - 128];
    else if (g == 1) v = (k < 128) ? Wih[(size_t)(128 + jj) * DD + k] : Whh[(size_t)(128 + jj) * DD + k - 128];
    else if (g == 2) v = (k < 128) ? Wih[(size_t)(256 + jj) * DD + k] : 0.f;
    else             v = (k < 128) ? 0.f : Whh[(size_t)(256 + jj) * DD + k - 128];
    Bswz[idx] = f2b(v);
}

// ---------------- 3 GRU steps per dispatch; h carried in LDS (bf16), no registers ----------------
// h staged once per dispatch from Ah; handed between steps via the LDS h-half
// (epilogue reads its own h_old from LDS, then overwrites it); Ah written once at
// dispatch end. Last step (t=11) accumulates the final linear instead.
__global__ __launch_bounds__(256, 2) void gru_mfma_kernel(
    const uint* __restrict__ Agall, int tbase,
    uint* __restrict__ Ah, const ushort* __restrict__ Bswz,
    const float* __restrict__ bih, const float* __restrict__ bhh,
    const float* __restrict__ wl, const float* __restrict__ bl,
    float* __restrict__ out)
{
    __shared__ ushort sA[64 * 256];   // 32 KB: row = 512B [g(256B) | h(256B)], XOR-swizzled
    __shared__ float outacc[64];
    const int tid = threadIdx.x;
    const int w = tid >> 6, l = tid & 63;
    const int n0 = blockIdx.x * 64;

    if (tid < 64) outacc[tid] = 0.f;
    // stage h-half from Ah (bf16 h_{tbase-1})
    #pragma unroll
    for (int i = 0; i < 4; i++) {
        int flat = tid + 256 * i;          // 0..1023 = 64 rows x 16 chunks
        int row = flat >> 4, gc = flat & 15;
        int n = n0 + row;
        uint4 vh = make_uint4(0u, 0u, 0u, 0u);
        if (n < NN) vh = *(const uint4*)&Ah[(size_t)n * 64 + gc * 4];
        int sw = (row & 7) << 4;
        *(uint4*)((char*)sA + row * 512 + ((256 + gc * 16) ^ sw)) = vh;
    }

    // per-thread constants (2 output columns)
    const int jjA[2] = { (2 * w) * 16 + (l & 15), (2 * w + 1) * 16 + (l & 15) };
    float brc[2], bzc[2], binc[2], bhnc[2], wlc[2];
    #pragma unroll
    for (int s = 0; s < 2; s++) {
        brc[s]  = bih[jjA[s]] + bhh[jjA[s]];
        bzc[s]  = bih[128 + jjA[s]] + bhh[128 + jjA[s]];
        binc[s] = bih[256 + jjA[s]];
        bhnc[s] = bhh[256 + jjA[s]];
        wlc[s]  = wl[jjA[s]];
    }

    const bf16x8* Bf = (const bf16x8*)Bswz;

    #pragma unroll 1
    for (int tt = 0; tt < 3; tt++) {
        const int t = tbase + tt;
        const uint* Agp = Agall + (size_t)t * NN * 64;
        // stage g-half (h-half epilogue writes become visible at the barrier)
        #pragma unroll
        for (int i = 0; i < 4; i++) {
            int flat = tid + 256 * i;
            int row = flat >> 4, gc = flat & 15;
            int n = n0 + row;
            uint4 vg = make_uint4(0u, 0u, 0u, 0u);
            if (n < NN) vg = *(const uint4*)&Agp[(size_t)n * 64 + gc * 4];
            int sw = (row & 7) << 4;
            *(uint4*)((char*)sA + row * 512 + ((gc * 16) ^ sw)) = vg;
        }
        __syncthreads();

        f32x4 acc[4][4][2];
        #pragma unroll
        for (int i = 0; i < 4; i++)
            #pragma unroll
            for (int g = 0; g < 4; g++)
                #pragma unroll
                for (int s = 0; s < 2; s++)
                    acc[i][g][s] = (f32x4){0.f, 0.f, 0.f, 0.f};

        #pragma unroll
        for (int kb = 0; kb < 8; kb++) {
            bf16x8 a[4];
            #pragma unroll
            for (int i = 0; i < 4; i++) {
                int rl = i * 16 + (l & 15);
                int byteoff = rl * 512 + (((kb * 64) + ((l >> 4) * 16)) ^ ((rl & 7) << 4));
                a[i] = *(const bf16x8*)((const char*)sA + byteoff);
            }
            bf16x8 b[4][2];
            #pragma unroll
            for (int g = 0; g < 4; g++)
                #pragma unroll
                for (int s = 0; s < 2; s++)
                    b[g][s] = Bf[(size_t)(kb * 32 + g * 8 + 2 * w + s) * 64 + l];
            #pragma unroll
            for (int i = 0; i < 4; i++)
                #pragma unroll
                for (int g = 0; g < 4; g++)
                    #pragma unroll
                    for (int s = 0; s < 2; s++)
                        acc[i][g][s] = __builtin_amdgcn_mfma_f32_16x16x32_bf16(
                            a[i], b[g][s], acc[i][g][s], 0, 0, 0);
        }
        __syncthreads();   // all waves done reading sA before h-half is overwritten

        const bool lastT = (t == TT - 1);
        #pragma unroll
        for (int s = 0; s < 2; s++) {
            const int jj = jjA[s];
            const int hc = 16 + (jj >> 3);
            const int hb = (jj & 7) * 2;
            #pragma unroll
            for (int i = 0; i < 4; i++) {
                #pragma unroll
                for (int r = 0; r < 4; r++) {
                    int row = i * 16 + (l >> 4) * 4 + r;
                    int n = n0 + row;
                    if (n >= NN) continue;
                    int hoff = row * 512 + ((hc * 16) ^ ((row & 7) << 4)) + hb;
                    float hold = b2f(*(const ushort*)((const char*)sA + hoff));
                    float rp = acc[i][0][s][r] + brc[s];
                    float zp = acc[i][1][s][r] + bzc[s];
                    float rg = 1.f / (1.f + __expf(-rp));
                    float zg = 1.f / (1.f + __expf(-zp));
                    float nv = tanhf(acc[i][2][s][r] + binc[s] + rg * (acc[i][3][s][r] + bhnc[s]));
                    float hnew = (1.f - zg) * nv + zg * hold;
                    if (lastT) {
                        atomicAdd(&outacc[row], hnew * wlc[s]);
                    } else {
                        ushort hb16 = f2b(hnew);
                        *(ushort*)((char*)sA + hoff) = hb16;
                        if (tt == 2) ((ushort*)Ah)[(size_t)n * 128 + jj] = hb16;
                    }
                }
            }
        }
    }

    if (tbase + 2 == TT - 1) {
        __syncthreads();
        int n = n0 + tid;
        if (tid < 64 && n < NN) out[n] = outacc[tid] + bl[0];
    }
}

extern "C" void kernel_launch(void* const* d_in, const int* in_sizes, int n_in,
                              void* d_out, int out_size, void* d_ws, size_t ws_size,
                              hipStream_t stream)
{
    const float* x     = (const float*)d_in[0];
    const int*   ei    = (const int*)d_in[1];
    const float* Wg    = (const float*)d_in[2];
    const float* a_src = (const float*)d_in[3];
    const float* a_dst = (const float*)d_in[4];
    const float* b_gat = (const float*)d_in[5];
    const float* Wih   = (const float*)d_in[6];
    const float* Whh   = (const float*)d_in[7];
    const float* bih   = (const float*)d_in[8];
    const float* bhh   = (const float*)d_in[9];
    const float* Wl    = (const float*)d_in[10];
    const float* bl    = (const float*)d_in[11];
    float* out = (float*)d_out;

    char* ws = (char*)d_ws;
    float* alsrc   = (float*)ws;                                  ws += (size_t)MTOT * HH * 4;        // 9.6 MB
    float* aldst   = (float*)ws;                                  ws += (size_t)MTOT * HH * 4;        // 9.6 MB
    uint* Agall    = (uint*)ws;                                   ws += (size_t)MTOT * 64 * 4;        // 153.6 MB
    uint* Ah       = (uint*)ws;                                   ws += (size_t)NN * 64 * 4;          // 12.8 MB
    ushort* Bswz   = (ushort*)ws;                                 ws += 131072 * 2;
    ushort* Wgh    = (ushort*)ws;                                 ws += 16384 * 2;
    ushort* Wgl    = (ushort*)ws;                                 ws += 16384 * 2;
    ushort* hbf    = (ushort*)ws;                                 ws += (size_t)MTOT * DD * 2;        // 153.6 MB
    int* cur       = (int*)ws;                                    ws += (size_t)TT * NB * 4;
    uint* bbuf     = (uint*)ws;                                   ws += (size_t)TT * NB * CAPB * 4;   // 57.7 MB

    hipMemsetAsync(Ah, 0, (size_t)NN * 64 * sizeof(uint), stream);

    init_cur_kernel<<<(TT * NB + 255) / 256, 256, 0, stream>>>(cur);
    prep_b_kernel<<<512, 256, 0, stream>>>(Wih, Whh, Bswz);
    prep_wg_kernel<<<64, 256, 0, stream>>>(Wg, Wgh, Wgl);

    gemm_all_kernel<<<MTOT / 64, 256, 0, stream>>>(x, Wgh, Wgl, a_src, a_dst, hbf, alsrc, aldst);

    fill2_kernel<<<TT * FB2, 512, 0, stream>>>(ei, cur, bbuf);
    gather_all_kernel<<<GGRID, 512, 0, stream>>>(
        cur, bbuf, alsrc, aldst, (const uint*)hbf, b_gat, Agall);

    for (int tb = 0; tb < TT; tb += 3) {
        gru_mfma_kernel<<<(NN + 63) / 64, 256, 0, stream>>>(
            Agall, tb, Ah, Bswz, bih, bhh, Wl, bl, out);
    }
}

// Round 17
// 1104.307 us; speedup vs baseline: 1.6293x; 1.6293x over previous
//
#include <hip/hip_runtime.h>
#include <cstddef>

#define NN 50000
#define TT 12
#define FIN 128
#define DD 128
#define HH 4
#define EE 800000
#define MTOT (NN * TT)          // 600000 rows, divisible by 64
#define NEG 0.2f

#define BSH 6                   // bucket = dst >> 6 (64 nodes per bucket)
#define NB 782                  // ceil(50000/64)
#define CAPB 1536               // fixed region entries per (t,bucket); mean 1023, 16 sigma margin
#define BMAX CAPB
#define EPB2 8192               // edges per fill block
#define FB2 98                  // 98*8192 >= 800000
#define GGRID (TT * NB)         // 9384 = 8 * 1173 exactly
#define GPX (GGRID / 8)         // 1173 blocks per XCD slice

typedef __attribute__((ext_vector_type(8))) short bf16x8;
typedef __attribute__((ext_vector_type(4))) float f32x4;

__device__ __forceinline__ ushort f2b(float x) {
    unsigned int u = __builtin_bit_cast(unsigned int, x);
    unsigned int r = (u + 0x7FFFu + ((u >> 16) & 1u)) >> 16;
    return (ushort)r;
}
__device__ __forceinline__ float b2f(ushort u) {
    unsigned int v = ((unsigned int)u) << 16;
    return __builtin_bit_cast(float, v);
}

// ---------------- prep: W_gat in MFMA fragment order, hi/lo bf16 split ----------------
__global__ __launch_bounds__(256) void prep_wg_kernel(
    const float* __restrict__ Wg, ushort* __restrict__ Wgh, ushort* __restrict__ Wgl)
{
    int idx = blockIdx.x * 256 + threadIdx.x;      // < 16384
    int fi = idx >> 9, rem = idx & 511;
    int l = rem >> 3, j = rem & 7;
    int kb = fi >> 3, cf = fi & 7;
    int k = kb * 32 + (l >> 4) * 8 + j;
    int col = cf * 16 + (l & 15);
    float v = Wg[(size_t)k * DD + col];
    ushort hi = f2b(v);
    Wgh[idx] = hi;
    Wgl[idx] = f2b(v - b2f(hi));
}

// ---------------- all-t GAT GEMM + fused attention logits ----------------
__global__ __launch_bounds__(256) void gemm_all_kernel(
    const float* __restrict__ x, const ushort* __restrict__ Wgh, const ushort* __restrict__ Wgl,
    const float* __restrict__ a_src, const float* __restrict__ a_dst,
    ushort* __restrict__ hbf, float* __restrict__ alsrc, float* __restrict__ aldst)
{
    __shared__ ushort sAh[64 * 128];   // 16 KB
    const int tid = threadIdx.x;
    const int w = tid >> 6, l = tid & 63;
    const int m0 = blockIdx.x * 64;

    #pragma unroll
    for (int i = 0; i < 8; i++) {
        int fl = tid + 256 * i;            // 0..2047 = 64 rows x 32 float4
        int row = fl >> 5, q = fl & 31;
        float4 v = *(const float4*)&x[(size_t)(m0 + row) * FIN + q * 4];
        ushort hi[4] = {f2b(v.x), f2b(v.y), f2b(v.z), f2b(v.w)};
        int byteoff = row * 256 + ((q * 8) ^ ((row & 7) << 4));
        *(uint2*)((char*)sAh + byteoff) = *(uint2*)hi;
    }
    __syncthreads();

    f32x4 acc[4][2];
    #pragma unroll
    for (int i = 0; i < 4; i++)
        #pragma unroll
        for (int s = 0; s < 2; s++) acc[i][s] = (f32x4){0.f, 0.f, 0.f, 0.f};

    const bf16x8* Bh = (const bf16x8*)Wgh;
    const bf16x8* Bl = (const bf16x8*)Wgl;
    #pragma unroll
    for (int kb = 0; kb < 4; kb++) {
        bf16x8 ah[4];
        #pragma unroll
        for (int i = 0; i < 4; i++) {
            int rl = i * 16 + (l & 15);
            int byteoff = rl * 256 + (((kb * 64) + ((l >> 4) * 16)) ^ ((rl & 7) << 4));
            ah[i] = *(const bf16x8*)((const char*)sAh + byteoff);
        }
        bf16x8 bh[2], bl[2];
        #pragma unroll
        for (int s = 0; s < 2; s++) {
            int fi = kb * 8 + 2 * w + s;
            bh[s] = Bh[(size_t)fi * 64 + l];
            bl[s] = Bl[(size_t)fi * 64 + l];
        }
        #pragma unroll
        for (int i = 0; i < 4; i++)
            #pragma unroll
            for (int s = 0; s < 2; s++) {
                acc[i][s] = __builtin_amdgcn_mfma_f32_16x16x32_bf16(ah[i], bh[s], acc[i][s], 0, 0, 0);
                acc[i][s] = __builtin_amdgcn_mfma_f32_16x16x32_bf16(ah[i], bl[s], acc[i][s], 0, 0, 0);
            }
    }

    // hbf write (bf16, t-plane)
    #pragma unroll
    for (int i = 0; i < 4; i++)
        #pragma unroll
        for (int s = 0; s < 2; s++) {
            int jj = (2 * w + s) * 16 + (l & 15);
            #pragma unroll
            for (int r = 0; r < 4; r++) {
                int m = m0 + i * 16 + (l >> 4) * 4 + r;
                int n = m / TT;
                int t = m - n * TT;
                hbf[((size_t)t * NN + n) * DD + jj] = f2b(acc[i][s][r]);
            }
        }

    // fused attention logits: head = w; 16-lane butterfly reduce
    const float as0 = a_src[w * 32 + (l & 15)];
    const float as1 = a_src[w * 32 + 16 + (l & 15)];
    const float ad0 = a_dst[w * 32 + (l & 15)];
    const float ad1 = a_dst[w * 32 + 16 + (l & 15)];
    #pragma unroll
    for (int i = 0; i < 4; i++) {
        #pragma unroll
        for (int r = 0; r < 4; r++) {
            float p1 = acc[i][0][r] * as0 + acc[i][1][r] * as1;
            float p2 = acc[i][0][r] * ad0 + acc[i][1][r] * ad1;
            #pragma unroll
            for (int mk = 1; mk < 16; mk <<= 1) {
                p1 += __shfl_xor(p1, mk);
                p2 += __shfl_xor(p2, mk);
            }
            if ((l & 15) == 0) {
                int m = m0 + i * 16 + (l >> 4) * 4 + r;
                int n = m / TT;
                int t = m - n * TT;
                size_t base = ((size_t)t * NN + n) * 4 + w;
                alsrc[base] = p1;
                aldst[base] = p2;
            }
        }
    }
}

// ---------------- init per-(t,bucket) cursor ----------------
__global__ __launch_bounds__(256) void init_cur_kernel(int* __restrict__ cur)
{
    int i = blockIdx.x * 256 + threadIdx.x;
    if (i < TT * NB) cur[i] = i * CAPB;
}

// ---------------- single-pass bucket fill: LDS histogram + per-(block,bin) cursor runs ----------------
__global__ __launch_bounds__(512) void fill2_kernel(
    const int* __restrict__ ei, int* __restrict__ cur, uint* __restrict__ bbuf)
{
    __shared__ int hcnt[NB];
    __shared__ int hbase[NB];
    const int t = blockIdx.x / FB2;
    const int blk = blockIdx.x - t * FB2;
    const int tid = threadIdx.x;
    const int* srcp = ei + (size_t)t * 2 * EE;
    const int* dstp = srcp + EE;

    for (int b = tid; b < NB; b += 512) hcnt[b] = 0;
    __syncthreads();

    const int ebase = blk * EPB2;
    uint vals[16];
    #pragma unroll
    for (int k = 0; k < 16; k++) {
        int e = ebase + k * 512 + tid;
        uint v = 0xffffffffu;
        if (e < EE) {
            int s = srcp[e];
            int d = dstp[e];
            v = ((uint)d << 16) | (uint)s;
            atomicAdd(&hcnt[d >> BSH], 1);
        }
        vals[k] = v;
    }
    __syncthreads();
    for (int b = tid; b < NB; b += 512) {
        int c = hcnt[b];
        if (c > 0) hbase[b] = atomicAdd(&cur[t * NB + b], c);
        hcnt[b] = 0;
    }
    __syncthreads();
    #pragma unroll
    for (int k = 0; k < 16; k++) {
        uint v = vals[k];
        if (v != 0xffffffffu) {
            int b = v >> 22;
            int r = atomicAdd(&hcnt[b], 1);
            bbuf[hbase[b] + r] = v;
        }
    }
}

// ---------------- fused GAT aggregate, ALL t: in-LDS sort + register accumulate ----------------
// XCD-aware block swizzle; per-edge exp recompute hides under gather load latency;
// unroll-4 inner loop for load ILP (R16-verified: VALUBusy 73->86%).
__global__ __launch_bounds__(512) void gather_all_kernel(
    const int* __restrict__ cur, const uint* __restrict__ bbuf,
    const float* __restrict__ alsrc_a, const float* __restrict__ aldst_a,
    const uint* __restrict__ hbf32_a, const float* __restrict__ bgat,
    uint* __restrict__ Ag_a)
{
    __shared__ uint ent[BMAX];        // 6 KB
    __shared__ ushort ssrc[BMAX];     // 3 KB
    __shared__ int h64[64];
    __shared__ int p64[65];
    __shared__ int cur64[64];
    const int bid = blockIdx.x;
    const int swz = (bid & 7) * GPX + (bid >> 3);
    const int t = swz / NB;
    const int bkt = swz - t * NB;
    const int ci = t * NB + bkt;
    const int tid = threadIdx.x;
    const int dbase = bkt << BSH;

    const float* alsrc = alsrc_a + (size_t)t * NN * HH;
    const float* aldst = aldst_a + (size_t)t * NN * HH;
    const uint* hbf32 = hbf32_a + (size_t)t * NN * 64;
    uint* Ag = Ag_a + (size_t)t * NN * 64;

    const int lo0 = ci * CAPB;
    int cnt = cur[ci] - lo0;
    if (cnt > BMAX) cnt = BMAX;

    if (tid < 64) h64[tid] = 0;
    __syncthreads();
    for (int i = tid; i < cnt; i += 512) {
        uint e = bbuf[lo0 + i];
        ent[i] = e;
        atomicAdd(&h64[(e >> 16) & 63], 1);
    }
    __syncthreads();
    if (tid < 64) {
        int v = h64[tid];
        #pragma unroll
        for (int off = 1; off < 64; off <<= 1) {
            int u = __shfl_up(v, off);
            if (tid >= off) v += u;
        }
        p64[tid + 1] = v;
        if (tid == 0) p64[0] = 0;
        cur64[tid] = v - h64[tid];   // exclusive prefix
    }
    __syncthreads();
    for (int i = tid; i < cnt; i += 512) {
        uint e = ent[i];
        int pos = atomicAdd(&cur64[(e >> 16) & 63], 1);
        ssrc[pos] = (ushort)(e & 0xffffu);
    }
    __syncthreads();

    const int w = tid >> 6, lane = tid & 63, hd = lane >> 4;
    const float bg0 = bgat[2 * lane], bg1 = bgat[2 * lane + 1];
    for (int q = 0; q < 8; q++) {
        int nd = w * 8 + q;
        int d = dbase + nd;
        if (d >= NN) break;
        float adh = aldst[(size_t)d * 4 + hd];
        // self-loop init
        float a = alsrc[(size_t)d * 4 + hd] + adh;
        a = fmaxf(a, NEG * a);
        float wt = __expf(a);
        float den = wt;
        uint hw = hbf32[(size_t)d * 64 + lane];
        float acc0 = __builtin_bit_cast(float, hw << 16) * wt;
        float acc1 = __builtin_bit_cast(float, hw & 0xffff0000u) * wt;
        const int e1 = p64[nd + 1];
        #pragma unroll 4
        for (int e = p64[nd]; e < e1; e++) {
            int s = ssrc[e];
            float aa = alsrc[(size_t)s * 4 + hd] + adh;
            aa = fmaxf(aa, NEG * aa);
            float wgt = __expf(aa);
            uint hh = hbf32[(size_t)s * 64 + lane];
            acc0 += __builtin_bit_cast(float, hh << 16) * wgt;
            acc1 += __builtin_bit_cast(float, hh & 0xffff0000u) * wgt;
            den += wgt;
        }
        float invd = 1.f / (den + 1e-16f);
        float g0 = fmaxf(acc0 * invd + bg0, 0.f);
        float g1 = fmaxf(acc1 * invd + bg1, 0.f);
        Ag[(size_t)d * 64 + lane] = (uint)f2b(g0) | ((uint)f2b(g1) << 16);
    }
}

// ---------------- prep: bf16 gate matrix in MFMA fragment order ----------------
__global__ __launch_bounds__(256) void prep_b_kernel(
    const float* __restrict__ Wih, const float* __restrict__ Whh, ushort* __restrict__ Bswz)
{
    int idx = blockIdx.x * 256 + threadIdx.x;      // < 131072
    int fi = idx >> 9;
    int rem = idx & 511;
    int l = rem >> 3, j = rem & 7;
    int kb = fi >> 5, c = fi & 31;
    int g = c >> 3, cf = c & 7;
    int k = kb * 32 + (l >> 4) * 8 + j;
    int jj = cf * 16 + (l & 15);
    float v;
    if (g == 0)      v = (k < 128) ? Wih[(size_t)jj * DD + k]         : Whh[(size_t)jj * DD + k - 128];
    else if (g == 1) v = (k < 128) ? Wih[(size_t)(128 + jj) * DD + k] : Whh[(size_t)(128 + jj) * DD + k - 128];
    else if (g == 2) v = (k < 128) ? Wih[(size_t)(256 + jj) * DD + k] : 0.f;
    else             v = (k < 128) ? 0.f : Whh[(size_t)(256 + jj) * DD + k - 128];
    Bswz[idx] = f2b(v);
}

// ---------------- fused GRU step via bf16 MFMA (R14/R15 form) ----------------
// g staged from Ag plane; h-half staged directly from fp32 hstate (on-the-fly bf16
// convert — no Ah buffer). last=1: skip hstate write, fuse final linear.
__global__ __launch_bounds__(256, 2) void gru_mfma_kernel(
    const uint* __restrict__ Agp, const ushort* __restrict__ Bswz,
    float* __restrict__ hstate, const float* __restrict__ bih, const float* __restrict__ bhh,
    const float* __restrict__ wl, const float* __restrict__ bl,
    float* __restrict__ out, int last)
{
    __shared__ ushort sA[64 * 256];   // 32 KB
    __shared__ float outacc[64];
    const int tid = threadIdx.x;
    const int w = tid >> 6, l = tid & 63;
    const int n0 = blockIdx.x * 64;

    if (tid < 64) outacc[tid] = 0.f;
    #pragma unroll
    for (int i = 0; i < 4; i++) {
        int flat = tid + 256 * i;          // 0..1023 = 64 rows x 16 chunks of 8 elems
        int row = flat >> 4, gc = flat & 15;
        int n = n0 + row;
        uint4 vg = make_uint4(0u, 0u, 0u, 0u);
        ushort hv[8] = {0, 0, 0, 0, 0, 0, 0, 0};
        if (n < NN) {
            vg = *(const uint4*)&Agp[(size_t)n * 64 + gc * 4];
            float4 ha = *(const float4*)&hstate[(size_t)n * DD + gc * 8];
            float4 hb = *(const float4*)&hstate[(size_t)n * DD + gc * 8 + 4];
            hv[0] = f2b(ha.x); hv[1] = f2b(ha.y); hv[2] = f2b(ha.z); hv[3] = f2b(ha.w);
            hv[4] = f2b(hb.x); hv[5] = f2b(hb.y); hv[6] = f2b(hb.z); hv[7] = f2b(hb.w);
        }
        int sw = (row & 7) << 4;
        *(uint4*)((char*)sA + row * 512 + ((gc * 16) ^ sw)) = vg;
        *(uint4*)((char*)sA + row * 512 + ((256 + gc * 16) ^ sw)) = *(uint4*)hv;
    }
    __syncthreads();

    f32x4 acc[4][4][2];
    #pragma unroll
    for (int i = 0; i < 4; i++)
        #pragma unroll
        for (int g = 0; g < 4; g++)
            #pragma unroll
            for (int s = 0; s < 2; s++)
                acc[i][g][s] = (f32x4){0.f, 0.f, 0.f, 0.f};

    const bf16x8* Bf = (const bf16x8*)Bswz;
    #pragma unroll
    for (int kb = 0; kb < 8; kb++) {
        bf16x8 a[4];
        #pragma unroll
        for (int i = 0; i < 4; i++) {
            int rl = i * 16 + (l & 15);
            int byteoff = rl * 512 + (((kb * 64) + ((l >> 4) * 16)) ^ ((rl & 7) << 4));
            a[i] = *(const bf16x8*)((const char*)sA + byteoff);
        }
        bf16x8 b[4][2];
        #pragma unroll
        for (int g = 0; g < 4; g++)
            #pragma unroll
            for (int s = 0; s < 2; s++)
                b[g][s] = Bf[(size_t)(kb * 32 + g * 8 + 2 * w + s) * 64 + l];
        #pragma unroll
        for (int i = 0; i < 4; i++)
            #pragma unroll
            for (int g = 0; g < 4; g++)
                #pragma unroll
                for (int s = 0; s < 2; s++)
                    acc[i][g][s] = __builtin_amdgcn_mfma_f32_16x16x32_bf16(
                        a[i], b[g][s], acc[i][g][s], 0, 0, 0);
    }

    #pragma unroll
    for (int s = 0; s < 2; s++) {
        int jj = (2 * w + s) * 16 + (l & 15);
        float br  = bih[jj] + bhh[jj];
        float bz  = bih[128 + jj] + bhh[128 + jj];
        float bin = bih[256 + jj];
        float bhn = bhh[256 + jj];
        float wlc = wl[jj];
        #pragma unroll
        for (int i = 0; i < 4; i++) {
            #pragma unroll
            for (int r = 0; r < 4; r++) {
                int row = i * 16 + (l >> 4) * 4 + r;
                int n = n0 + row;
                if (n >= NN) continue;
                float rp = acc[i][0][s][r] + br;
                float zp = acc[i][1][s][r] + bz;
                float rg = 1.f / (1.f + __expf(-rp));
                float zg = 1.f / (1.f + __expf(-zp));
                float nv = tanhf(acc[i][2][s][r] + bin + rg * (acc[i][3][s][r] + bhn));
                float hold = hstate[(size_t)n * DD + jj];
                float hnew = (1.f - zg) * nv + zg * hold;
                if (!last) hstate[(size_t)n * DD + jj] = hnew;
                else atomicAdd(&outacc[row], hnew * wlc);
            }
        }
    }
    if (last) {
        __syncthreads();
        int n = n0 + tid;
        if (tid < 64 && n < NN) out[n] = outacc[tid] + bl[0];
    }
}

extern "C" void kernel_launch(void* const* d_in, const int* in_sizes, int n_in,
                              void* d_out, int out_size, void* d_ws, size_t ws_size,
                              hipStream_t stream)
{
    const float* x     = (const float*)d_in[0];
    const int*   ei    = (const int*)d_in[1];
    const float* Wg    = (const float*)d_in[2];
    const float* a_src = (const float*)d_in[3];
    const float* a_dst = (const float*)d_in[4];
    const float* b_gat = (const float*)d_in[5];
    const float* Wih   = (const float*)d_in[6];
    const float* Whh   = (const float*)d_in[7];
    const float* bih   = (const float*)d_in[8];
    const float* bhh   = (const float*)d_in[9];
    const float* Wl    = (const float*)d_in[10];
    const float* bl    = (const float*)d_in[11];
    float* out = (float*)d_out;

    char* ws = (char*)d_ws;
    float* hstate  = (float*)ws;                                  ws += (size_t)NN * DD * 4;          // 25.6 MB
    float* alsrc   = (float*)ws;                                  ws += (size_t)MTOT * HH * 4;        // 9.6 MB
    float* aldst   = (float*)ws;                                  ws += (size_t)MTOT * HH * 4;        // 9.6 MB
    uint* Agall    = (uint*)ws;                                   ws += (size_t)MTOT * 64 * 4;        // 153.6 MB
    ushort* Bswz   = (ushort*)ws;                                 ws += 131072 * 2;
    ushort* Wgh    = (ushort*)ws;                                 ws += 16384 * 2;
    ushort* Wgl    = (ushort*)ws;                                 ws += 16384 * 2;
    ushort* hbf    = (ushort*)ws;                                 ws += (size_t)MTOT * DD * 2;        // 153.6 MB
    int* cur       = (int*)ws;                                    ws += (size_t)TT * NB * 4;
    uint* bbuf     = (uint*)ws;                                   ws += (size_t)TT * NB * CAPB * 4;   // 57.7 MB

    hipMemsetAsync(hstate, 0, (size_t)NN * DD * sizeof(float), stream);

    init_cur_kernel<<<(TT * NB + 255) / 256, 256, 0, stream>>>(cur);
    prep_b_kernel<<<512, 256, 0, stream>>>(Wih, Whh, Bswz);
    prep_wg_kernel<<<64, 256, 0, stream>>>(Wg, Wgh, Wgl);

    gemm_all_kernel<<<MTOT / 64, 256, 0, stream>>>(x, Wgh, Wgl, a_src, a_dst, hbf, alsrc, aldst);

    fill2_kernel<<<TT * FB2, 512, 0, stream>>>(ei, cur, bbuf);
    gather_all_kernel<<<GGRID, 512, 0, stream>>>(
        cur, bbuf, alsrc, aldst, (const uint*)hbf, b_gat, Agall);

    for (int t = 0; t < TT; t++) {
        gru_mfma_kernel<<<(NN + 63) / 64, 256, 0, stream>>>(
            Agall + (size_t)t * NN * 64, Bswz, hstate, bih, bhh, Wl, bl, out, t == TT - 1);
    }
}

// Round 18
// 1018.665 us; speedup vs baseline: 1.7662x; 1.0841x over previous
//
#include <hip/hip_runtime.h>
#include <cstddef>

#define NN 50000
#define TT 12
#define FIN 128
#define DD 128
#define HH 4
#define EE 800000
#define MTOT (NN * TT)          // 600000 rows, divisible by 64
#define NEG 0.2f

#define BSH 6                   // bucket = dst >> 6 (64 nodes per bucket)
#define NB 782                  // ceil(50000/64)
#define CAPB 1536               // fixed region entries per (t,bucket); mean 1023, 16 sigma margin
#define BMAX CAPB
#define EPB2 8192               // edges per fill block
#define FB2 98                  // 98*8192 >= 800000
#define GGRID (TT * NB)         // 9384 = 8 * 1173 exactly
#define GPX (GGRID / 8)         // 1173 blocks per XCD slice

typedef __attribute__((ext_vector_type(8))) short bf16x8;
typedef __attribute__((ext_vector_type(4))) float f32x4;

__device__ __forceinline__ ushort f2b(float x) {
    unsigned int u = __builtin_bit_cast(unsigned int, x);
    unsigned int r = (u + 0x7FFFu + ((u >> 16) & 1u)) >> 16;
    return (ushort)r;
}
__device__ __forceinline__ float b2f(ushort u) {
    unsigned int v = ((unsigned int)u) << 16;
    return __builtin_bit_cast(float, v);
}

// ---------------- prep: W_gat in MFMA fragment order, hi/lo bf16 split ----------------
__global__ __launch_bounds__(256) void prep_wg_kernel(
    const float* __restrict__ Wg, ushort* __restrict__ Wgh, ushort* __restrict__ Wgl)
{
    int idx = blockIdx.x * 256 + threadIdx.x;      // < 16384
    int fi = idx >> 9, rem = idx & 511;
    int l = rem >> 3, j = rem & 7;
    int kb = fi >> 3, cf = fi & 7;
    int k = kb * 32 + (l >> 4) * 8 + j;
    int col = cf * 16 + (l & 15);
    float v = Wg[(size_t)k * DD + col];
    ushort hi = f2b(v);
    Wgh[idx] = hi;
    Wgl[idx] = f2b(v - b2f(hi));
}

// ---------------- all-t GAT GEMM + fused attention logits ----------------
__global__ __launch_bounds__(256) void gemm_all_kernel(
    const float* __restrict__ x, const ushort* __restrict__ Wgh, const ushort* __restrict__ Wgl,
    const float* __restrict__ a_src, const float* __restrict__ a_dst,
    ushort* __restrict__ hbf, float* __restrict__ alsrc, float* __restrict__ aldst)
{
    __shared__ ushort sAh[64 * 128];   // 16 KB
    const int tid = threadIdx.x;
    const int w = tid >> 6, l = tid & 63;
    const int m0 = blockIdx.x * 64;

    #pragma unroll
    for (int i = 0; i < 8; i++) {
        int fl = tid + 256 * i;            // 0..2047 = 64 rows x 32 float4
        int row = fl >> 5, q = fl & 31;
        float4 v = *(const float4*)&x[(size_t)(m0 + row) * FIN + q * 4];
        ushort hi[4] = {f2b(v.x), f2b(v.y), f2b(v.z), f2b(v.w)};
        int byteoff = row * 256 + ((q * 8) ^ ((row & 7) << 4));
        *(uint2*)((char*)sAh + byteoff) = *(uint2*)hi;
    }
    __syncthreads();

    f32x4 acc[4][2];
    #pragma unroll
    for (int i = 0; i < 4; i++)
        #pragma unroll
        for (int s = 0; s < 2; s++) acc[i][s] = (f32x4){0.f, 0.f, 0.f, 0.f};

    const bf16x8* Bh = (const bf16x8*)Wgh;
    const bf16x8* Bl = (const bf16x8*)Wgl;
    #pragma unroll
    for (int kb = 0; kb < 4; kb++) {
        bf16x8 ah[4];
        #pragma unroll
        for (int i = 0; i < 4; i++) {
            int rl = i * 16 + (l & 15);
            int byteoff = rl * 256 + (((kb * 64) + ((l >> 4) * 16)) ^ ((rl & 7) << 4));
            ah[i] = *(const bf16x8*)((const char*)sAh + byteoff);
        }
        bf16x8 bh[2], bl[2];
        #pragma unroll
        for (int s = 0; s < 2; s++) {
            int fi = kb * 8 + 2 * w + s;
            bh[s] = Bh[(size_t)fi * 64 + l];
            bl[s] = Bl[(size_t)fi * 64 + l];
        }
        #pragma unroll
        for (int i = 0; i < 4; i++)
            #pragma unroll
            for (int s = 0; s < 2; s++) {
                acc[i][s] = __builtin_amdgcn_mfma_f32_16x16x32_bf16(ah[i], bh[s], acc[i][s], 0, 0, 0);
                acc[i][s] = __builtin_amdgcn_mfma_f32_16x16x32_bf16(ah[i], bl[s], acc[i][s], 0, 0, 0);
            }
    }

    // hbf write (bf16, t-plane)
    #pragma unroll
    for (int i = 0; i < 4; i++)
        #pragma unroll
        for (int s = 0; s < 2; s++) {
            int jj = (2 * w + s) * 16 + (l & 15);
            #pragma unroll
            for (int r = 0; r < 4; r++) {
                int m = m0 + i * 16 + (l >> 4) * 4 + r;
                int n = m / TT;
                int t = m - n * TT;
                hbf[((size_t)t * NN + n) * DD + jj] = f2b(acc[i][s][r]);
            }
        }

    // fused attention logits: head = w; 16-lane butterfly reduce
    const float as0 = a_src[w * 32 + (l & 15)];
    const float as1 = a_src[w * 32 + 16 + (l & 15)];
    const float ad0 = a_dst[w * 32 + (l & 15)];
    const float ad1 = a_dst[w * 32 + 16 + (l & 15)];
    #pragma unroll
    for (int i = 0; i < 4; i++) {
        #pragma unroll
        for (int r = 0; r < 4; r++) {
            float p1 = acc[i][0][r] * as0 + acc[i][1][r] * as1;
            float p2 = acc[i][0][r] * ad0 + acc[i][1][r] * ad1;
            #pragma unroll
            for (int mk = 1; mk < 16; mk <<= 1) {
                p1 += __shfl_xor(p1, mk);
                p2 += __shfl_xor(p2, mk);
            }
            if ((l & 15) == 0) {
                int m = m0 + i * 16 + (l >> 4) * 4 + r;
                int n = m / TT;
                int t = m - n * TT;
                size_t base = ((size_t)t * NN + n) * 4 + w;
                alsrc[base] = p1;
                aldst[base] = p2;
            }
        }
    }
}

// ---------------- init per-(t,bucket) cursor ----------------
__global__ __launch_bounds__(256) void init_cur_kernel(int* __restrict__ cur)
{
    int i = blockIdx.x * 256 + threadIdx.x;
    if (i < TT * NB) cur[i] = i * CAPB;
}

// ---------------- single-pass bucket fill: LDS histogram + per-(block,bin) cursor runs ----------------
__global__ __launch_bounds__(512) void fill2_kernel(
    const int* __restrict__ ei, int* __restrict__ cur, uint* __restrict__ bbuf)
{
    __shared__ int hcnt[NB];
    __shared__ int hbase[NB];
    const int t = blockIdx.x / FB2;
    const int blk = blockIdx.x - t * FB2;
    const int tid = threadIdx.x;
    const int* srcp = ei + (size_t)t * 2 * EE;
    const int* dstp = srcp + EE;

    for (int b = tid; b < NB; b += 512) hcnt[b] = 0;
    __syncthreads();

    const int ebase = blk * EPB2;
    uint vals[16];
    #pragma unroll
    for (int k = 0; k < 16; k++) {
        int e = ebase + k * 512 + tid;
        uint v = 0xffffffffu;
        if (e < EE) {
            int s = srcp[e];
            int d = dstp[e];
            v = ((uint)d << 16) | (uint)s;
            atomicAdd(&hcnt[d >> BSH], 1);
        }
        vals[k] = v;
    }
    __syncthreads();
    for (int b = tid; b < NB; b += 512) {
        int c = hcnt[b];
        if (c > 0) hbase[b] = atomicAdd(&cur[t * NB + b], c);
        hcnt[b] = 0;
    }
    __syncthreads();
    #pragma unroll
    for (int k = 0; k < 16; k++) {
        uint v = vals[k];
        if (v != 0xffffffffu) {
            int b = v >> 22;
            int r = atomicAdd(&hcnt[b], 1);
            bbuf[hbase[b] + r] = v;
        }
    }
}

// ---------------- fused GAT aggregate, ALL t: in-LDS sort + register accumulate ----------------
// XCD-aware block swizzle; per-edge exp recompute hides under gather load latency;
// unroll-4 inner loop for load ILP (R16-verified: VALUBusy 73->86%).
__global__ __launch_bounds__(512) void gather_all_kernel(
    const int* __restrict__ cur, const uint* __restrict__ bbuf,
    const float* __restrict__ alsrc_a, const float* __restrict__ aldst_a,
    const uint* __restrict__ hbf32_a, const float* __restrict__ bgat,
    uint* __restrict__ Ag_a)
{
    __shared__ uint ent[BMAX];        // 6 KB
    __shared__ ushort ssrc[BMAX];     // 3 KB
    __shared__ int h64[64];
    __shared__ int p64[65];
    __shared__ int cur64[64];
    const int bid = blockIdx.x;
    const int swz = (bid & 7) * GPX + (bid >> 3);
    const int t = swz / NB;
    const int bkt = swz - t * NB;
    const int ci = t * NB + bkt;
    const int tid = threadIdx.x;
    const int dbase = bkt << BSH;

    const float* alsrc = alsrc_a + (size_t)t * NN * HH;
    const float* aldst = aldst_a + (size_t)t * NN * HH;
    const uint* hbf32 = hbf32_a + (size_t)t * NN * 64;
    uint* Ag = Ag_a + (size_t)t * NN * 64;

    const int lo0 = ci * CAPB;
    int cnt = cur[ci] - lo0;
    if (cnt > BMAX) cnt = BMAX;

    if (tid < 64) h64[tid] = 0;
    __syncthreads();
    for (int i = tid; i < cnt; i += 512) {
        uint e = bbuf[lo0 + i];
        ent[i] = e;
        atomicAdd(&h64[(e >> 16) & 63], 1);
    }
    __syncthreads();
    if (tid < 64) {
        int v = h64[tid];
        #pragma unroll
        for (int off = 1; off < 64; off <<= 1) {
            int u = __shfl_up(v, off);
            if (tid >= off) v += u;
        }
        p64[tid + 1] = v;
        if (tid == 0) p64[0] = 0;
        cur64[tid] = v - h64[tid];   // exclusive prefix
    }
    __syncthreads();
    for (int i = tid; i < cnt; i += 512) {
        uint e = ent[i];
        int pos = atomicAdd(&cur64[(e >> 16) & 63], 1);
        ssrc[pos] = (ushort)(e & 0xffffu);
    }
    __syncthreads();

    const int w = tid >> 6, lane = tid & 63, hd = lane >> 4;
    const float bg0 = bgat[2 * lane], bg1 = bgat[2 * lane + 1];
    for (int q = 0; q < 8; q++) {
        int nd = w * 8 + q;
        int d = dbase + nd;
        if (d >= NN) break;
        float adh = aldst[(size_t)d * 4 + hd];
        // self-loop init
        float a = alsrc[(size_t)d * 4 + hd] + adh;
        a = fmaxf(a, NEG * a);
        float wt = __expf(a);
        float den = wt;
        uint hw = hbf32[(size_t)d * 64 + lane];
        float acc0 = __builtin_bit_cast(float, hw << 16) * wt;
        float acc1 = __builtin_bit_cast(float, hw & 0xffff0000u) * wt;
        const int e1 = p64[nd + 1];
        #pragma unroll 4
        for (int e = p64[nd]; e < e1; e++) {
            int s = ssrc[e];
            float aa = alsrc[(size_t)s * 4 + hd] + adh;
            aa = fmaxf(aa, NEG * aa);
            float wgt = __expf(aa);
            uint hh = hbf32[(size_t)s * 64 + lane];
            acc0 += __builtin_bit_cast(float, hh << 16) * wgt;
            acc1 += __builtin_bit_cast(float, hh & 0xffff0000u) * wgt;
            den += wgt;
        }
        float invd = 1.f / (den + 1e-16f);
        float g0 = fmaxf(acc0 * invd + bg0, 0.f);
        float g1 = fmaxf(acc1 * invd + bg1, 0.f);
        Ag[(size_t)d * 64 + lane] = (uint)f2b(g0) | ((uint)f2b(g1) << 16);
    }
}

// ---------------- prep: bf16 gate matrix in MFMA fragment order ----------------
__global__ __launch_bounds__(256) void prep_b_kernel(
    const float* __restrict__ Wih, const float* __restrict__ Whh, ushort* __restrict__ Bswz)
{
    int idx = blockIdx.x * 256 + threadIdx.x;      // < 131072
    int fi = idx >> 9;
    int rem = idx & 511;
    int l = rem >> 3, j = rem & 7;
    int kb = fi >> 5, c = fi & 31;
    int g = c >> 3, cf = c & 7;
    int k = kb * 32 + (l >> 4) * 8 + j;
    int jj = cf * 16 + (l & 15);
    float v;
    if (g == 0)      v = (k < 128) ? Wih[(size_t)jj * DD + k]         : Whh[(size_t)jj * DD + k - 128];
    else if (g == 1) v = (k < 128) ? Wih[(size_t)(128 + jj) * DD + k] : Whh[(size_t)(128 + jj) * DD + k - 128];
    else if (g == 2) v = (k < 128) ? Wih[(size_t)(256 + jj) * DD + k] : 0.f;
    else             v = (k < 128) ? 0.f : Whh[(size_t)(256 + jj) * DD + k - 128];
    Bswz[idx] = f2b(v);
}

// ---------------- fused GRU step via bf16 MFMA — 512 threads, 1 col-slice/wave ----------------
// 8 waves, each owns col-frag w (16 cols) of every gate: acc[4][4] (64 VGPR acc vs 128).
// Same math as R17 (col-frag relabel 2w+s -> w); better occupancy for the serial chain.
__global__ __launch_bounds__(512) void gru_mfma_kernel(
    const uint* __restrict__ Agp, const ushort* __restrict__ Bswz,
    float* __restrict__ hstate, const float* __restrict__ bih, const float* __restrict__ bhh,
    const float* __restrict__ wl, const float* __restrict__ bl,
    float* __restrict__ out, int last)
{
    __shared__ ushort sA[64 * 256];   // 32 KB
    __shared__ float outacc[64];
    const int tid = threadIdx.x;
    const int w = tid >> 6, l = tid & 63;
    const int n0 = blockIdx.x * 64;

    if (tid < 64) outacc[tid] = 0.f;
    #pragma unroll
    for (int i = 0; i < 2; i++) {
        int flat = tid + 512 * i;          // 0..1023 = 64 rows x 16 chunks of 8 elems
        int row = flat >> 4, gc = flat & 15;
        int n = n0 + row;
        uint4 vg = make_uint4(0u, 0u, 0u, 0u);
        ushort hv[8] = {0, 0, 0, 0, 0, 0, 0, 0};
        if (n < NN) {
            vg = *(const uint4*)&Agp[(size_t)n * 64 + gc * 4];
            float4 ha = *(const float4*)&hstate[(size_t)n * DD + gc * 8];
            float4 hb = *(const float4*)&hstate[(size_t)n * DD + gc * 8 + 4];
            hv[0] = f2b(ha.x); hv[1] = f2b(ha.y); hv[2] = f2b(ha.z); hv[3] = f2b(ha.w);
            hv[4] = f2b(hb.x); hv[5] = f2b(hb.y); hv[6] = f2b(hb.z); hv[7] = f2b(hb.w);
        }
        int sw = (row & 7) << 4;
        *(uint4*)((char*)sA + row * 512 + ((gc * 16) ^ sw)) = vg;
        *(uint4*)((char*)sA + row * 512 + ((256 + gc * 16) ^ sw)) = *(uint4*)hv;
    }
    __syncthreads();

    f32x4 acc[4][4];
    #pragma unroll
    for (int i = 0; i < 4; i++)
        #pragma unroll
        for (int g = 0; g < 4; g++)
            acc[i][g] = (f32x4){0.f, 0.f, 0.f, 0.f};

    const bf16x8* Bf = (const bf16x8*)Bswz;
    #pragma unroll
    for (int kb = 0; kb < 8; kb++) {
        bf16x8 a[4];
        #pragma unroll
        for (int i = 0; i < 4; i++) {
            int rl = i * 16 + (l & 15);
            int byteoff = rl * 512 + (((kb * 64) + ((l >> 4) * 16)) ^ ((rl & 7) << 4));
            a[i] = *(const bf16x8*)((const char*)sA + byteoff);
        }
        bf16x8 b[4];
        #pragma unroll
        for (int g = 0; g < 4; g++)
            b[g] = Bf[(size_t)(kb * 32 + g * 8 + w) * 64 + l];
        #pragma unroll
        for (int i = 0; i < 4; i++)
            #pragma unroll
            for (int g = 0; g < 4; g++)
                acc[i][g] = __builtin_amdgcn_mfma_f32_16x16x32_bf16(
                    a[i], b[g], acc[i][g], 0, 0, 0);
    }

    const int jj = w * 16 + (l & 15);
    const float br  = bih[jj] + bhh[jj];
    const float bz  = bih[128 + jj] + bhh[128 + jj];
    const float bin = bih[256 + jj];
    const float bhn = bhh[256 + jj];
    const float wlc = wl[jj];
    #pragma unroll
    for (int i = 0; i < 4; i++) {
        #pragma unroll
        for (int r = 0; r < 4; r++) {
            int row = i * 16 + (l >> 4) * 4 + r;
            int n = n0 + row;
            if (n >= NN) continue;
            float rp = acc[i][0][r] + br;
            float zp = acc[i][1][r] + bz;
            float rg = 1.f / (1.f + __expf(-rp));
            float zg = 1.f / (1.f + __expf(-zp));
            float nv = tanhf(acc[i][2][r] + bin + rg * (acc[i][3][r] + bhn));
            float hold = hstate[(size_t)n * DD + jj];
            float hnew = (1.f - zg) * nv + zg * hold;
            if (!last) hstate[(size_t)n * DD + jj] = hnew;
            else atomicAdd(&outacc[row], hnew * wlc);
        }
    }
    if (last) {
        __syncthreads();
        int n = n0 + tid;
        if (tid < 64 && n < NN) out[n] = outacc[tid] + bl[0];
    }
}

extern "C" void kernel_launch(void* const* d_in, const int* in_sizes, int n_in,
                              void* d_out, int out_size, void* d_ws, size_t ws_size,
                              hipStream_t stream)
{
    const float* x     = (const float*)d_in[0];
    const int*   ei    = (const int*)d_in[1];
    const float* Wg    = (const float*)d_in[2];
    const float* a_src = (const float*)d_in[3];
    const float* a_dst = (const float*)d_in[4];
    const float* b_gat = (const float*)d_in[5];
    const float* Wih   = (const float*)d_in[6];
    const float* Whh   = (const float*)d_in[7];
    const float* bih   = (const float*)d_in[8];
    const float* bhh   = (const float*)d_in[9];
    const float* Wl    = (const float*)d_in[10];
    const float* bl    = (const float*)d_in[11];
    float* out = (float*)d_out;

    char* ws = (char*)d_ws;
    float* hstate  = (float*)ws;                                  ws += (size_t)NN * DD * 4;          // 25.6 MB
    float* alsrc   = (float*)ws;                                  ws += (size_t)MTOT * HH * 4;        // 9.6 MB
    float* aldst   = (float*)ws;                                  ws += (size_t)MTOT * HH * 4;        // 9.6 MB
    uint* Agall    = (uint*)ws;                                   ws += (size_t)MTOT * 64 * 4;        // 153.6 MB
    ushort* Bswz   = (ushort*)ws;                                 ws += 131072 * 2;
    ushort* Wgh    = (ushort*)ws;                                 ws += 16384 * 2;
    ushort* Wgl    = (ushort*)ws;                                 ws += 16384 * 2;
    ushort* hbf    = (ushort*)ws;                                 ws += (size_t)MTOT * DD * 2;        // 153.6 MB
    int* cur       = (int*)ws;                                    ws += (size_t)TT * NB * 4;
    uint* bbuf     = (uint*)ws;                                   ws += (size_t)TT * NB * CAPB * 4;   // 57.7 MB

    hipMemsetAsync(hstate, 0, (size_t)NN * DD * sizeof(float), stream);

    init_cur_kernel<<<(TT * NB + 255) / 256, 256, 0, stream>>>(cur);
    prep_b_kernel<<<512, 256, 0, stream>>>(Wih, Whh, Bswz);
    prep_wg_kernel<<<64, 256, 0, stream>>>(Wg, Wgh, Wgl);

    gemm_all_kernel<<<MTOT / 64, 256, 0, stream>>>(x, Wgh, Wgl, a_src, a_dst, hbf, alsrc, aldst);

    fill2_kernel<<<TT * FB2, 512, 0, stream>>>(ei, cur, bbuf);
    gather_all_kernel<<<GGRID, 512, 0, stream>>>(
        cur, bbuf, alsrc, aldst, (const uint*)hbf, b_gat, Agall);

    for (int t = 0; t < TT; t++) {
        gru_mfma_kernel<<<(NN + 63) / 64, 512, 0, stream>>>(
            Agall + (size_t)t * NN * 64, Bswz, hstate, bih, bhh, Wl, bl, out, t == TT - 1);
    }
}

// Round 19
// 975.125 us; speedup vs baseline: 1.8451x; 1.0447x over previous
//
#include <hip/hip_runtime.h>
#include <cstddef>

#define NN 50000
#define TT 12
#define FIN 128
#define DD 128
#define HH 4
#define EE 800000
#define MTOT (NN * TT)          // 600000 rows, divisible by 64
#define NEG 0.2f

#define BSH 6                   // bucket = dst >> 6 (64 nodes per bucket)
#define NB 782                  // ceil(50000/64)
#define CAPB 1536               // fixed region entries per (t,bucket); mean 1023, 16 sigma margin
#define BMAX CAPB
#define EPB2 8192               // edges per fill block
#define FB2 98                  // 98*8192 >= 800000
#define GGRID (TT * NB)         // 9384 = 8 * 1173 exactly
#define GPX (GGRID / 8)         // 1173 blocks per XCD slice

typedef __attribute__((ext_vector_type(8))) short bf16x8;
typedef __attribute__((ext_vector_type(4))) float f32x4;

__device__ __forceinline__ ushort f2b(float x) {
    unsigned int u = __builtin_bit_cast(unsigned int, x);
    unsigned int r = (u + 0x7FFFu + ((u >> 16) & 1u)) >> 16;
    return (ushort)r;
}
__device__ __forceinline__ float b2f(ushort u) {
    unsigned int v = ((unsigned int)u) << 16;
    return __builtin_bit_cast(float, v);
}

// ---------------- prep: W_gat in MFMA fragment order, hi/lo bf16 split ----------------
__global__ __launch_bounds__(256) void prep_wg_kernel(
    const float* __restrict__ Wg, ushort* __restrict__ Wgh, ushort* __restrict__ Wgl)
{
    int idx = blockIdx.x * 256 + threadIdx.x;      // < 16384
    int fi = idx >> 9, rem = idx & 511;
    int l = rem >> 3, j = rem & 7;
    int kb = fi >> 3, cf = fi & 7;
    int k = kb * 32 + (l >> 4) * 8 + j;
    int col = cf * 16 + (l & 15);
    float v = Wg[(size_t)k * DD + col];
    ushort hi = f2b(v);
    Wgh[idx] = hi;
    Wgl[idx] = f2b(v - b2f(hi));
}

// ---------------- all-t GAT GEMM + fused attention logits ----------------
__global__ __launch_bounds__(256) void gemm_all_kernel(
    const float* __restrict__ x, const ushort* __restrict__ Wgh, const ushort* __restrict__ Wgl,
    const float* __restrict__ a_src, const float* __restrict__ a_dst,
    ushort* __restrict__ hbf, float* __restrict__ alsrc, float* __restrict__ aldst)
{
    __shared__ ushort sAh[64 * 128];   // 16 KB
    const int tid = threadIdx.x;
    const int w = tid >> 6, l = tid & 63;
    const int m0 = blockIdx.x * 64;

    #pragma unroll
    for (int i = 0; i < 8; i++) {
        int fl = tid + 256 * i;            // 0..2047 = 64 rows x 32 float4
        int row = fl >> 5, q = fl & 31;
        float4 v = *(const float4*)&x[(size_t)(m0 + row) * FIN + q * 4];
        ushort hi[4] = {f2b(v.x), f2b(v.y), f2b(v.z), f2b(v.w)};
        int byteoff = row * 256 + ((q * 8) ^ ((row & 7) << 4));
        *(uint2*)((char*)sAh + byteoff) = *(uint2*)hi;
    }
    __syncthreads();

    f32x4 acc[4][2];
    #pragma unroll
    for (int i = 0; i < 4; i++)
        #pragma unroll
        for (int s = 0; s < 2; s++) acc[i][s] = (f32x4){0.f, 0.f, 0.f, 0.f};

    const bf16x8* Bh = (const bf16x8*)Wgh;
    const bf16x8* Bl = (const bf16x8*)Wgl;
    #pragma unroll
    for (int kb = 0; kb < 4; kb++) {
        bf16x8 ah[4];
        #pragma unroll
        for (int i = 0; i < 4; i++) {
            int rl = i * 16 + (l & 15);
            int byteoff = rl * 256 + (((kb * 64) + ((l >> 4) * 16)) ^ ((rl & 7) << 4));
            ah[i] = *(const bf16x8*)((const char*)sAh + byteoff);
        }
        bf16x8 bh[2], bl[2];
        #pragma unroll
        for (int s = 0; s < 2; s++) {
            int fi = kb * 8 + 2 * w + s;
            bh[s] = Bh[(size_t)fi * 64 + l];
            bl[s] = Bl[(size_t)fi * 64 + l];
        }
        #pragma unroll
        for (int i = 0; i < 4; i++)
            #pragma unroll
            for (int s = 0; s < 2; s++) {
                acc[i][s] = __builtin_amdgcn_mfma_f32_16x16x32_bf16(ah[i], bh[s], acc[i][s], 0, 0, 0);
                acc[i][s] = __builtin_amdgcn_mfma_f32_16x16x32_bf16(ah[i], bl[s], acc[i][s], 0, 0, 0);
            }
    }

    // hbf write (bf16, t-plane)
    #pragma unroll
    for (int i = 0; i < 4; i++)
        #pragma unroll
        for (int s = 0; s < 2; s++) {
            int jj = (2 * w + s) * 16 + (l & 15);
            #pragma unroll
            for (int r = 0; r < 4; r++) {
                int m = m0 + i * 16 + (l >> 4) * 4 + r;
                int n = m / TT;
                int t = m - n * TT;
                hbf[((size_t)t * NN + n) * DD + jj] = f2b(acc[i][s][r]);
            }
        }

    // fused attention logits: head = w; 16-lane butterfly reduce
    const float as0 = a_src[w * 32 + (l & 15)];
    const float as1 = a_src[w * 32 + 16 + (l & 15)];
    const float ad0 = a_dst[w * 32 + (l & 15)];
    const float ad1 = a_dst[w * 32 + 16 + (l & 15)];
    #pragma unroll
    for (int i = 0; i < 4; i++) {
        #pragma unroll
        for (int r = 0; r < 4; r++) {
            float p1 = acc[i][0][r] * as0 + acc[i][1][r] * as1;
            float p2 = acc[i][0][r] * ad0 + acc[i][1][r] * ad1;
            #pragma unroll
            for (int mk = 1; mk < 16; mk <<= 1) {
                p1 += __shfl_xor(p1, mk);
                p2 += __shfl_xor(p2, mk);
            }
            if ((l & 15) == 0) {
                int m = m0 + i * 16 + (l >> 4) * 4 + r;
                int n = m / TT;
                int t = m - n * TT;
                size_t base = ((size_t)t * NN + n) * 4 + w;
                alsrc[base] = p1;
                aldst[base] = p2;
            }
        }
    }
}

// ---------------- init per-(t,bucket) cursor ----------------
__global__ __launch_bounds__(256) void init_cur_kernel(int* __restrict__ cur)
{
    int i = blockIdx.x * 256 + threadIdx.x;
    if (i < TT * NB) cur[i] = i * CAPB;
}

// ---------------- single-pass bucket fill: LDS histogram + per-(block,bin) cursor runs ----------------
__global__ __launch_bounds__(512) void fill2_kernel(
    const int* __restrict__ ei, int* __restrict__ cur, uint* __restrict__ bbuf)
{
    __shared__ int hcnt[NB];
    __shared__ int hbase[NB];
    const int t = blockIdx.x / FB2;
    const int blk = blockIdx.x - t * FB2;
    const int tid = threadIdx.x;
    const int* srcp = ei + (size_t)t * 2 * EE;
    const int* dstp = srcp + EE;

    for (int b = tid; b < NB; b += 512) hcnt[b] = 0;
    __syncthreads();

    const int ebase = blk * EPB2;
    uint vals[16];
    #pragma unroll
    for (int k = 0; k < 16; k++) {
        int e = ebase + k * 512 + tid;
        uint v = 0xffffffffu;
        if (e < EE) {
            int s = srcp[e];
            int d = dstp[e];
            v = ((uint)d << 16) | (uint)s;
            atomicAdd(&hcnt[d >> BSH], 1);
        }
        vals[k] = v;
    }
    __syncthreads();
    for (int b = tid; b < NB; b += 512) {
        int c = hcnt[b];
        if (c > 0) hbase[b] = atomicAdd(&cur[t * NB + b], c);
        hcnt[b] = 0;
    }
    __syncthreads();
    #pragma unroll
    for (int k = 0; k < 16; k++) {
        uint v = vals[k];
        if (v != 0xffffffffu) {
            int b = v >> 22;
            int r = atomicAdd(&hcnt[b], 1);
            bbuf[hbase[b] + r] = v;
        }
    }
}

// ---------------- fused GAT aggregate, ALL t: in-LDS sort + register accumulate ----------------
// XCD-aware block swizzle; per-edge exp recompute hides under gather load latency;
// unroll-4 inner loop for load ILP (R16-verified: VALUBusy 73->86%).
__global__ __launch_bounds__(512) void gather_all_kernel(
    const int* __restrict__ cur, const uint* __restrict__ bbuf,
    const float* __restrict__ alsrc_a, const float* __restrict__ aldst_a,
    const uint* __restrict__ hbf32_a, const float* __restrict__ bgat,
    uint* __restrict__ Ag_a)
{
    __shared__ uint ent[BMAX];        // 6 KB
    __shared__ ushort ssrc[BMAX];     // 3 KB
    __shared__ int h64[64];
    __shared__ int p64[65];
    __shared__ int cur64[64];
    const int bid = blockIdx.x;
    const int swz = (bid & 7) * GPX + (bid >> 3);
    const int t = swz / NB;
    const int bkt = swz - t * NB;
    const int ci = t * NB + bkt;
    const int tid = threadIdx.x;
    const int dbase = bkt << BSH;

    const float* alsrc = alsrc_a + (size_t)t * NN * HH;
    const float* aldst = aldst_a + (size_t)t * NN * HH;
    const uint* hbf32 = hbf32_a + (size_t)t * NN * 64;
    uint* Ag = Ag_a + (size_t)t * NN * 64;

    const int lo0 = ci * CAPB;
    int cnt = cur[ci] - lo0;
    if (cnt > BMAX) cnt = BMAX;

    if (tid < 64) h64[tid] = 0;
    __syncthreads();
    for (int i = tid; i < cnt; i += 512) {
        uint e = bbuf[lo0 + i];
        ent[i] = e;
        atomicAdd(&h64[(e >> 16) & 63], 1);
    }
    __syncthreads();
    if (tid < 64) {
        int v = h64[tid];
        #pragma unroll
        for (int off = 1; off < 64; off <<= 1) {
            int u = __shfl_up(v, off);
            if (tid >= off) v += u;
        }
        p64[tid + 1] = v;
        if (tid == 0) p64[0] = 0;
        cur64[tid] = v - h64[tid];   // exclusive prefix
    }
    __syncthreads();
    for (int i = tid; i < cnt; i += 512) {
        uint e = ent[i];
        int pos = atomicAdd(&cur64[(e >> 16) & 63], 1);
        ssrc[pos] = (ushort)(e & 0xffffu);
    }
    __syncthreads();

    const int w = tid >> 6, lane = tid & 63, hd = lane >> 4;
    const float bg0 = bgat[2 * lane], bg1 = bgat[2 * lane + 1];
    for (int q = 0; q < 8; q++) {
        int nd = w * 8 + q;
        int d = dbase + nd;
        if (d >= NN) break;
        float adh = aldst[(size_t)d * 4 + hd];
        // self-loop init
        float a = alsrc[(size_t)d * 4 + hd] + adh;
        a = fmaxf(a, NEG * a);
        float wt = __expf(a);
        float den = wt;
        uint hw = hbf32[(size_t)d * 64 + lane];
        float acc0 = __builtin_bit_cast(float, hw << 16) * wt;
        float acc1 = __builtin_bit_cast(float, hw & 0xffff0000u) * wt;
        const int e1 = p64[nd + 1];
        #pragma unroll 4
        for (int e = p64[nd]; e < e1; e++) {
            int s = ssrc[e];
            float aa = alsrc[(size_t)s * 4 + hd] + adh;
            aa = fmaxf(aa, NEG * aa);
            float wgt = __expf(aa);
            uint hh = hbf32[(size_t)s * 64 + lane];
            acc0 += __builtin_bit_cast(float, hh << 16) * wgt;
            acc1 += __builtin_bit_cast(float, hh & 0xffff0000u) * wgt;
            den += wgt;
        }
        float invd = 1.f / (den + 1e-16f);
        float g0 = fmaxf(acc0 * invd + bg0, 0.f);
        float g1 = fmaxf(acc1 * invd + bg1, 0.f);
        Ag[(size_t)d * 64 + lane] = (uint)f2b(g0) | ((uint)f2b(g1) << 16);
    }
}

// ---------------- prep: bf16 gate matrix in MFMA fragment order ----------------
__global__ __launch_bounds__(256) void prep_b_kernel(
    const float* __restrict__ Wih, const float* __restrict__ Whh, ushort* __restrict__ Bswz)
{
    int idx = blockIdx.x * 256 + threadIdx.x;      // < 131072
    int fi = idx >> 9;
    int rem = idx & 511;
    int l = rem >> 3, j = rem & 7;
    int kb = fi >> 5, c = fi & 31;
    int g = c >> 3, cf = c & 7;
    int k = kb * 32 + (l >> 4) * 8 + j;
    int jj = cf * 16 + (l & 15);
    float v;
    if (g == 0)      v = (k < 128) ? Wih[(size_t)jj * DD + k]         : Whh[(size_t)jj * DD + k - 128];
    else if (g == 1) v = (k < 128) ? Wih[(size_t)(128 + jj) * DD + k] : Whh[(size_t)(128 + jj) * DD + k - 128];
    else if (g == 2) v = (k < 128) ? Wih[(size_t)(256 + jj) * DD + k] : 0.f;
    else             v = (k < 128) ? 0.f : Whh[(size_t)(256 + jj) * DD + k - 128];
    Bswz[idx] = f2b(v);
}

// ---------------- fused GRU step via bf16 MFMA — 512 threads, bf16-only h (Ah) ----------------
// 8 waves, each owns col-frag w of every gate. h staged from bf16 Ah (same uint4 path
// as g); epilogue reads h_old from the LDS h-half (written pre-barrier, never modified
// after — no extra barrier needed; R16 proved bf16-h accuracy-safe); writes bf16 Ah only.
__global__ __launch_bounds__(512) void gru_mfma_kernel(
    const uint* __restrict__ Agp, uint* __restrict__ Ah, const ushort* __restrict__ Bswz,
    const float* __restrict__ bih, const float* __restrict__ bhh,
    const float* __restrict__ wl, const float* __restrict__ bl,
    float* __restrict__ out, int last)
{
    __shared__ ushort sA[64 * 256];   // 32 KB: row = 512B [g(256B) | h(256B)], XOR-swizzled
    __shared__ float outacc[64];
    const int tid = threadIdx.x;
    const int w = tid >> 6, l = tid & 63;
    const int n0 = blockIdx.x * 64;

    if (tid < 64) outacc[tid] = 0.f;
    #pragma unroll
    for (int i = 0; i < 2; i++) {
        int flat = tid + 512 * i;          // 0..1023 = 64 rows x 16 chunks
        int row = flat >> 4, gc = flat & 15;
        int n = n0 + row;
        uint4 vg = make_uint4(0u, 0u, 0u, 0u), vh = make_uint4(0u, 0u, 0u, 0u);
        if (n < NN) {
            vg = *(const uint4*)&Agp[(size_t)n * 64 + gc * 4];
            vh = *(const uint4*)&Ah[(size_t)n * 64 + gc * 4];
        }
        int sw = (row & 7) << 4;
        *(uint4*)((char*)sA + row * 512 + ((gc * 16) ^ sw)) = vg;
        *(uint4*)((char*)sA + row * 512 + ((256 + gc * 16) ^ sw)) = vh;
    }
    __syncthreads();

    f32x4 acc[4][4];
    #pragma unroll
    for (int i = 0; i < 4; i++)
        #pragma unroll
        for (int g = 0; g < 4; g++)
            acc[i][g] = (f32x4){0.f, 0.f, 0.f, 0.f};

    const bf16x8* Bf = (const bf16x8*)Bswz;
    #pragma unroll
    for (int kb = 0; kb < 8; kb++) {
        bf16x8 a[4];
        #pragma unroll
        for (int i = 0; i < 4; i++) {
            int rl = i * 16 + (l & 15);
            int byteoff = rl * 512 + (((kb * 64) + ((l >> 4) * 16)) ^ ((rl & 7) << 4));
            a[i] = *(const bf16x8*)((const char*)sA + byteoff);
        }
        bf16x8 b[4];
        #pragma unroll
        for (int g = 0; g < 4; g++)
            b[g] = Bf[(size_t)(kb * 32 + g * 8 + w) * 64 + l];
        #pragma unroll
        for (int i = 0; i < 4; i++)
            #pragma unroll
            for (int g = 0; g < 4; g++)
                acc[i][g] = __builtin_amdgcn_mfma_f32_16x16x32_bf16(
                    a[i], b[g], acc[i][g], 0, 0, 0);
    }

    const int jj = w * 16 + (l & 15);
    const float br  = bih[jj] + bhh[jj];
    const float bz  = bih[128 + jj] + bhh[128 + jj];
    const float bin = bih[256 + jj];
    const float bhn = bhh[256 + jj];
    const float wlc = wl[jj];
    const int hc = 16 + (jj >> 3);
    const int hb = (jj & 7) * 2;
    #pragma unroll
    for (int i = 0; i < 4; i++) {
        #pragma unroll
        for (int r = 0; r < 4; r++) {
            int row = i * 16 + (l >> 4) * 4 + r;
            int n = n0 + row;
            if (n >= NN) continue;
            int hoff = row * 512 + ((hc * 16) ^ ((row & 7) << 4)) + hb;
            float hold = b2f(*(const ushort*)((const char*)sA + hoff));
            float rp = acc[i][0][r] + br;
            float zp = acc[i][1][r] + bz;
            float rg = 1.f / (1.f + __expf(-rp));
            float zg = 1.f / (1.f + __expf(-zp));
            float nv = tanhf(acc[i][2][r] + bin + rg * (acc[i][3][r] + bhn));
            float hnew = (1.f - zg) * nv + zg * hold;
            if (!last) ((ushort*)Ah)[(size_t)n * 128 + jj] = f2b(hnew);
            else atomicAdd(&outacc[row], hnew * wlc);
        }
    }
    if (last) {
        __syncthreads();
        int n = n0 + tid;
        if (tid < 64 && n < NN) out[n] = outacc[tid] + bl[0];
    }
}

extern "C" void kernel_launch(void* const* d_in, const int* in_sizes, int n_in,
                              void* d_out, int out_size, void* d_ws, size_t ws_size,
                              hipStream_t stream)
{
    const float* x     = (const float*)d_in[0];
    const int*   ei    = (const int*)d_in[1];
    const float* Wg    = (const float*)d_in[2];
    const float* a_src = (const float*)d_in[3];
    const float* a_dst = (const float*)d_in[4];
    const float* b_gat = (const float*)d_in[5];
    const float* Wih   = (const float*)d_in[6];
    const float* Whh   = (const float*)d_in[7];
    const float* bih   = (const float*)d_in[8];
    const float* bhh   = (const float*)d_in[9];
    const float* Wl    = (const float*)d_in[10];
    const float* bl    = (const float*)d_in[11];
    float* out = (float*)d_out;

    char* ws = (char*)d_ws;
    float* alsrc   = (float*)ws;                                  ws += (size_t)MTOT * HH * 4;        // 9.6 MB
    float* aldst   = (float*)ws;                                  ws += (size_t)MTOT * HH * 4;        // 9.6 MB
    uint* Agall    = (uint*)ws;                                   ws += (size_t)MTOT * 64 * 4;        // 153.6 MB
    uint* Ah       = (uint*)ws;                                   ws += (size_t)NN * 64 * 4;          // 12.8 MB
    ushort* Bswz   = (ushort*)ws;                                 ws += 131072 * 2;
    ushort* Wgh    = (ushort*)ws;                                 ws += 16384 * 2;
    ushort* Wgl    = (ushort*)ws;                                 ws += 16384 * 2;
    ushort* hbf    = (ushort*)ws;                                 ws += (size_t)MTOT * DD * 2;        // 153.6 MB
    int* cur       = (int*)ws;                                    ws += (size_t)TT * NB * 4;
    uint* bbuf     = (uint*)ws;                                   ws += (size_t)TT * NB * CAPB * 4;   // 57.7 MB

    hipMemsetAsync(Ah, 0, (size_t)NN * 64 * sizeof(uint), stream);

    init_cur_kernel<<<(TT * NB + 255) / 256, 256, 0, stream>>>(cur);
    prep_b_kernel<<<512, 256, 0, stream>>>(Wih, Whh, Bswz);
    prep_wg_kernel<<<64, 256, 0, stream>>>(Wg, Wgh, Wgl);

    gemm_all_kernel<<<MTOT / 64, 256, 0, stream>>>(x, Wgh, Wgl, a_src, a_dst, hbf, alsrc, aldst);

    fill2_kernel<<<TT * FB2, 512, 0, stream>>>(ei, cur, bbuf);
    gather_all_kernel<<<GGRID, 512, 0, stream>>>(
        cur, bbuf, alsrc, aldst, (const uint*)hbf, b_gat, Agall);

    for (int t = 0; t < TT; t++) {
        gru_mfma_kernel<<<(NN + 63) / 64, 512, 0, stream>>>(
            Agall + (size_t)t * NN * 64, Ah, Bswz, bih, bhh, Wl, bl, out, t == TT - 1);
    }
}